// Round 3
// baseline (251.268 us; speedup 1.0000x reference)
//
#include <hip/hip_runtime.h>
#include <stdint.h>

#define NB 16
#define NA 8400
#define NA_PAD 9216
#define NCH 84
#define NCLS 80
#define CANDN 2048
#define MAXDET 300

typedef unsigned long long u64;

// ---------------- workspace layout (bytes) ----------------
static const size_t OFF_KEYS = 0;
static const size_t OFF_CLS  = 1075200;
static const size_t OFF_TIDX = 1612800;
static const size_t OFF_TSC  = 1743872;
static const size_t OFF_CAND = 1874944;
static const size_t OFF_NMS  = 2661376;
static const size_t OFF_AREA = 3185664;
static const size_t OFF_VAL  = 3316736;
static const size_t OFF_M    = 3320832;
// total ~11.7 MB

// ---------- kernel 1: per-anchor class max + argmax, build sort key ----------
__global__ __launch_bounds__(256) void score_kernel(const float* __restrict__ pred,
                                                    u64* __restrict__ keys,
                                                    int* __restrict__ cls) {
  int a = blockIdx.x * 256 + threadIdx.x;
  int b = blockIdx.y;
  if (a >= NA) return;
  const float* p = pred + (size_t)b * (NCH * NA) + 4 * NA + a;
  float best = p[0];
  int bc = 0;
#pragma unroll 8
  for (int c = 1; c < NCLS; ++c) {
    float v = p[(size_t)c * NA];
    if (v > best) { best = v; bc = c; }  // strict > : first-index argmax
  }
  // descending score, ascending index on ties, via ascending uint64 sort
  keys[b * NA + a] = (((u64)(~__float_as_uint(best))) << 32) | (unsigned int)a;
  cls[b * NA + a] = bc;
}

// ---------- kernel 2: radix-select top-2048 + bitonic sort of the 2048 ----------
__global__ __launch_bounds__(1024) void select_kernel(const u64* __restrict__ keys,
                                                      int* __restrict__ tidx,
                                                      float* __restrict__ tsc) {
  __shared__ u64 skeys[NA];       // 67200 B
  __shared__ u64 sortbuf[CANDN];  // 16384 B
  __shared__ int hist[256];
  __shared__ int cum[256];
  __shared__ u64 sh_prefix;
  __shared__ int sh_k;
  __shared__ int sh_cnt;

  int b = blockIdx.x;
  int tid = threadIdx.x;
  int lane = tid & 63;

  for (int i = tid; i < NA; i += 1024) skeys[i] = keys[b * NA + i];
  if (tid == 0) { sh_prefix = 0; sh_k = CANDN; sh_cnt = 0; }
  __syncthreads();

  u64 prefix = 0;
  int k = CANDN;
  for (int shift = 56; shift >= 0; shift -= 8) {
    if (tid < 256) hist[tid] = 0;
    __syncthreads();
    u64 pmask = (shift == 56) ? 0ULL : (~0ULL << (shift + 8));
    for (int i = tid; i < NA_PAD; i += 1024) {
      bool act = false;
      int d = 0;
      if (i < NA) {
        u64 key = skeys[i];
        act = (key & pmask) == prefix;
        d = (int)((key >> shift) & 255);
      }
      // wave-aggregate same-digit counts (scores cluster -> few hot bins)
      u64 m = __ballot(act);
      if (m) {
#pragma unroll
        for (int bit = 0; bit < 8; ++bit) {
          u64 bb = __ballot((d >> bit) & 1);
          m &= ((d >> bit) & 1) ? bb : ~bb;
        }
        if (act && (m & ((1ULL << lane) - 1)) == 0ULL)
          atomicAdd(&hist[d], (int)__popcll(m));
      }
    }
    __syncthreads();
    // inclusive scan of 256 bins by wave 0 (4 bins/lane, shfl scan, no barriers)
    if (tid < 64) {
      int v0 = hist[tid * 4 + 0], v1 = hist[tid * 4 + 1];
      int v2 = hist[tid * 4 + 2], v3 = hist[tid * 4 + 3];
      int s0 = v0, s1 = s0 + v1, s2 = s1 + v2, s3 = s2 + v3;
      int tot = s3;
      for (int off = 1; off < 64; off <<= 1) {
        int t = __shfl_up(tot, off, 64);
        if (tid >= off) tot += t;
      }
      int base = tot - s3;  // exclusive prefix of this lane's 4-bin group
      cum[tid * 4 + 0] = base + s0;
      cum[tid * 4 + 1] = base + s1;
      cum[tid * 4 + 2] = base + s2;
      cum[tid * 4 + 3] = base + s3;
    }
    __syncthreads();
    if (tid < 256) {
      int c = cum[tid];
      int cprev = (tid == 0) ? 0 : cum[tid - 1];
      if (c >= k && cprev < k) {  // exactly one digit satisfies this
        sh_prefix = prefix | ((u64)tid << shift);
        sh_k = k - cprev;
      }
    }
    __syncthreads();
    prefix = sh_prefix;
    k = sh_k;
  }

  // prefix == exact 2048th-smallest key; keys distinct -> exactly 2048 pass
  for (int i = tid; i < NA_PAD; i += 1024) {
    bool act = false;
    u64 key = 0;
    if (i < NA) { key = skeys[i]; act = key <= prefix; }
    u64 mm = __ballot(act);
    if (mm) {
      int leader = __ffsll(mm) - 1;
      int base = 0;
      if (lane == leader) base = atomicAdd(&sh_cnt, (int)__popcll(mm));
      base = __shfl(base, leader, 64);
      if (act) sortbuf[base + (int)__popcll(mm & ((1ULL << lane) - 1))] = key;
    }
  }
  __syncthreads();

  // bitonic sort 2048 keys ascending, 1024 threads = 1 comparator each
  for (int kk = 2; kk <= CANDN; kk <<= 1) {
    for (int j = kk >> 1; j > 0; j >>= 1) {
      int low = tid & (j - 1);
      int i2 = ((tid ^ low) << 1) | low;
      int l = i2 | j;
      u64 a = sortbuf[i2];
      u64 c = sortbuf[l];
      bool asc = (i2 & kk) == 0;
      if ((a > c) == asc) { sortbuf[i2] = c; sortbuf[l] = a; }
      __syncthreads();
    }
  }

  for (int t = tid; t < CANDN; t += 1024) {
    u64 key = sortbuf[t];
    tidx[b * CANDN + t] = (int)(unsigned int)(key & 0xFFFFFFFFu);
    tsc[b * CANDN + t] = __uint_as_float(~(unsigned int)(key >> 32));
  }
}

// ---------- kernel 3: gather box, xyxy, nms-box, area, valid mask ----------
__global__ __launch_bounds__(256) void prep_kernel(const float* __restrict__ pred,
                                                   const int* __restrict__ tidx,
                                                   const float* __restrict__ tsc,
                                                   const int* __restrict__ cls,
                                                   const int* __restrict__ imgsz,
                                                   float* __restrict__ cand,
                                                   float4* __restrict__ nmsb,
                                                   float* __restrict__ area,
                                                   u64* __restrict__ vmask) {
  int k = blockIdx.x * 256 + threadIdx.x;
  int b = blockIdx.y;
  int o = b * CANDN + k;
  int idx = tidx[o];
  float score = tsc[o];
  const float* pb = pred + (size_t)b * (NCH * NA);
  float x = pb[0 * NA + idx];
  float y = pb[1 * NA + idx];
  float w = pb[2 * NA + idx];
  float h = pb[3 * NA + idx];
  float hw = __fmul_rn(w, 0.5f);
  float hh = __fmul_rn(h, 0.5f);
  float x1 = __fsub_rn(x, hw);
  float y1 = __fsub_rn(y, hh);
  float x2 = __fadd_rn(x, hw);
  float y2 = __fadd_rn(y, hh);
  float clsf = (float)cls[b * NA + idx];
  float inv = (float)(1.0 / (double)imgsz[0]);
  float nx1 = __fadd_rn(__fmul_rn(x1, inv), clsf);
  float ny1 = __fadd_rn(__fmul_rn(y1, inv), clsf);
  float nx2 = __fadd_rn(__fmul_rn(x2, inv), clsf);
  float ny2 = __fadd_rn(__fmul_rn(y2, inv), clsf);
  float ar = __fmul_rn(__fsub_rn(nx2, nx1), __fsub_rn(ny2, ny1));
  bool valid = score > 0.25f;
  cand[(size_t)o * 6 + 0] = x1;
  cand[(size_t)o * 6 + 1] = y1;
  cand[(size_t)o * 6 + 2] = x2;
  cand[(size_t)o * 6 + 3] = y2;
  cand[(size_t)o * 6 + 4] = score;
  cand[(size_t)o * 6 + 5] = clsf;
  nmsb[o] = make_float4(nx1, ny1, nx2, ny2);
  area[o] = ar;
  u64 bal = __ballot(valid);
  if ((threadIdx.x & 63) == 0) vmask[b * 32 + (k >> 6)] = bal;
}

// ---------- kernel 4: suppression bit-matrix M[i][word] ----------
__global__ __launch_bounds__(256) void iou_kernel(const float4* __restrict__ nmsb,
                                                  const float* __restrict__ area,
                                                  u64* __restrict__ M) {
  int i = blockIdx.x;
  int b = blockIdx.y;
  int wv = threadIdx.x >> 6;
  int lane = threadIdx.x & 63;
  int ob = b * CANDN;
  float4 bi = nmsb[ob + i];
  float ai = area[ob + i];
#pragma unroll
  for (int it = 0; it < 8; ++it) {
    int w = wv + it * 4;  // words 0..31
    int j = (w << 6) + lane;
    float4 bj = nmsb[ob + j];
    float aj = area[ob + j];
    float ix1 = fmaxf(bi.x, bj.x);
    float iy1 = fmaxf(bi.y, bj.y);
    float ix2 = fminf(bi.z, bj.z);
    float iy2 = fminf(bi.w, bj.w);
    float iw = fmaxf(__fsub_rn(ix2, ix1), 0.0f);
    float ih = fmaxf(__fsub_rn(iy2, iy1), 0.0f);
    float inter = __fmul_rn(iw, ih);
    float denom = __fadd_rn(__fsub_rn(__fadd_rn(ai, aj), inter), 1e-7f);
    float iou = __fdiv_rn(inter, denom);
    u64 bal = __ballot(iou > 0.45f);
    if (lane == 0) M[(((size_t)(ob + i)) << 5) + w] = bal;
  }
}

// ---------- kernel 5: jump scan with depth-4 speculative row prefetch ----------
__global__ __launch_bounds__(64) void scan_kernel(const u64* __restrict__ M,
                                                  const u64* __restrict__ vmaskg,
                                                  const float* __restrict__ cand,
                                                  float* __restrict__ out) {
  int b = blockIdx.x;
  int lane = threadIdx.x;
  // avail = valid & not-suppressed, distributed: lane w<32 holds word w
  u64 avail = (lane < 32) ? vmaskg[b * 32 + lane] : 0ULL;
  const u64* Mb = M + (((size_t)b * CANDN) << 5);
  int cnt = 0;

  while (cnt < MAXDET) {
    // ---- find up to 4 lowest available candidate indices ----
    int idx0 = -1, idx1 = -1, idx2 = -1, idx3 = -1;
    {
      u64 av = avail;
#pragma unroll
      for (int s = 0; s < 4; ++s) {
        u64 nz = __ballot(av != 0ULL);  // wave-uniform
        if (nz == 0ULL) break;
        int w0 = __ffsll(nz) - 1;
        u64 a0 = __shfl(av, w0);
        int is = (w0 << 6) + (__ffsll(a0) - 1);
        if (s == 0) idx0 = is; else if (s == 1) idx1 = is;
        else if (s == 2) idx2 = is; else idx3 = is;
        if (lane == w0) av &= (av - 1);  // clear lowest bit
      }
    }
    if (idx0 < 0) break;

    // ---- issue all speculative row loads concurrently ----
    u64 r0 = 0, r1 = 0, r2 = 0, r3 = 0;
    if (lane < 32) {
      r0 = Mb[((size_t)idx0 << 5) + lane];
      if (idx1 >= 0) r1 = Mb[((size_t)idx1 << 5) + lane];
      if (idx2 >= 0) r2 = Mb[((size_t)idx2 << 5) + lane];
      if (idx3 >= 0) r3 = Mb[((size_t)idx3 << 5) + lane];
    }

    // ---- apply in order; skip speculated indices that got suppressed ----
    // idx0 is definitely the next keep.
    if (lane == (idx0 >> 6)) avail &= ~(1ULL << (idx0 & 63));  // explicit self-clear
    avail &= ~r0;
    if (lane < 6)
      out[((size_t)(b * MAXDET + cnt)) * 6 + lane] =
          cand[((size_t)(b * CANDN + idx0)) * 6 + lane];
    cnt++;
    if (cnt >= MAXDET) break;

    if (idx1 >= 0) {
      bool mine = (lane == (idx1 >> 6)) && ((avail >> (idx1 & 63)) & 1ULL);
      if (__ballot(mine) != 0ULL) {  // idx1 survived r0 -> it IS the next keep
        if (lane == (idx1 >> 6)) avail &= ~(1ULL << (idx1 & 63));
        avail &= ~r1;
        if (lane < 6)
          out[((size_t)(b * MAXDET + cnt)) * 6 + lane] =
              cand[((size_t)(b * CANDN + idx1)) * 6 + lane];
        cnt++;
        if (cnt >= MAXDET) break;
      }
    }
    if (idx2 >= 0) {
      bool mine = (lane == (idx2 >> 6)) && ((avail >> (idx2 & 63)) & 1ULL);
      if (__ballot(mine) != 0ULL) {
        if (lane == (idx2 >> 6)) avail &= ~(1ULL << (idx2 & 63));
        avail &= ~r2;
        if (lane < 6)
          out[((size_t)(b * MAXDET + cnt)) * 6 + lane] =
              cand[((size_t)(b * CANDN + idx2)) * 6 + lane];
        cnt++;
        if (cnt >= MAXDET) break;
      }
    }
    if (idx3 >= 0) {
      bool mine = (lane == (idx3 >> 6)) && ((avail >> (idx3 & 63)) & 1ULL);
      if (__ballot(mine) != 0ULL) {
        if (lane == (idx3 >> 6)) avail &= ~(1ULL << (idx3 & 63));
        avail &= ~r3;
        if (lane < 6)
          out[((size_t)(b * MAXDET + cnt)) * 6 + lane] =
              cand[((size_t)(b * CANDN + idx3)) * 6 + lane];
        cnt++;
        if (cnt >= MAXDET) break;
      }
    }
  }

  // zero-fill remaining rows (out is poisoned, must be written every call)
  for (int x = cnt * 6 + lane; x < MAXDET * 6; x += 64)
    out[(size_t)b * (MAXDET * 6) + x] = 0.0f;
}

extern "C" void kernel_launch(void* const* d_in, const int* in_sizes, int n_in,
                              void* d_out, int out_size, void* d_ws, size_t ws_size,
                              hipStream_t stream) {
  (void)in_sizes; (void)n_in; (void)out_size; (void)ws_size;
  const float* pred = (const float*)d_in[0];
  const int* imgsz = (const int*)d_in[1];
  char* ws = (char*)d_ws;
  u64* keys = (u64*)(ws + OFF_KEYS);
  int* cls = (int*)(ws + OFF_CLS);
  int* tidx = (int*)(ws + OFF_TIDX);
  float* tsc = (float*)(ws + OFF_TSC);
  float* cand = (float*)(ws + OFF_CAND);
  float4* nmsb = (float4*)(ws + OFF_NMS);
  float* area = (float*)(ws + OFF_AREA);
  u64* vmask = (u64*)(ws + OFF_VAL);
  u64* M = (u64*)(ws + OFF_M);
  float* out = (float*)d_out;

  score_kernel<<<dim3((NA + 255) / 256, NB), 256, 0, stream>>>(pred, keys, cls);
  select_kernel<<<NB, 1024, 0, stream>>>(keys, tidx, tsc);
  prep_kernel<<<dim3(CANDN / 256, NB), 256, 0, stream>>>(pred, tidx, tsc, cls, imgsz,
                                                         cand, nmsb, area, vmask);
  iou_kernel<<<dim3(CANDN, NB), 256, 0, stream>>>(nmsb, area, M);
  scan_kernel<<<NB, 64, 0, stream>>>(M, vmask, cand, out);
}

// Round 4
// 164.957 us; speedup vs baseline: 1.5232x; 1.5232x over previous
//
#include <hip/hip_runtime.h>
#include <stdint.h>

#define NB 16
#define NA 8400
#define NA_PAD 9216
#define NCH 84
#define NCLS 80
#define CANDN 2048
#define MAXDET 300

typedef unsigned long long u64;

// ---------------- workspace layout (bytes) ----------------
static const size_t OFF_KEYS = 0;
static const size_t OFF_CLS  = 1075200;
static const size_t OFF_TIDX = 1612800;
static const size_t OFF_TSC  = 1743872;
static const size_t OFF_CAND = 1874944;
static const size_t OFF_NMS  = 2661376;
static const size_t OFF_AREA = 3185664;
static const size_t OFF_VAL  = 3316736;
static const size_t OFF_M    = 3320832;
// total ~11.7 MB

// ---------- kernel 1: per-anchor class max + argmax, build sort key ----------
__global__ __launch_bounds__(256) void score_kernel(const float* __restrict__ pred,
                                                    u64* __restrict__ keys,
                                                    int* __restrict__ cls) {
  int a = blockIdx.x * 256 + threadIdx.x;
  int b = blockIdx.y;
  if (a >= NA) return;
  const float* p = pred + (size_t)b * (NCH * NA) + 4 * NA + a;
  float best = p[0];
  int bc = 0;
#pragma unroll 8
  for (int c = 1; c < NCLS; ++c) {
    float v = p[(size_t)c * NA];
    if (v > best) { best = v; bc = c; }  // strict > : first-index argmax
  }
  // descending score, ascending index on ties, via ascending uint64 sort
  keys[b * NA + a] = (((u64)(~__float_as_uint(best))) << 32) | (unsigned int)a;
  cls[b * NA + a] = bc;
}

// ---------- kernel 2: radix-select top-2048 + bitonic sort of the 2048 ----------
__global__ __launch_bounds__(1024) void select_kernel(const u64* __restrict__ keys,
                                                      int* __restrict__ tidx,
                                                      float* __restrict__ tsc) {
  __shared__ u64 skeys[NA];       // 67200 B
  __shared__ u64 sortbuf[CANDN];  // 16384 B
  __shared__ int hist[256];
  __shared__ int cum[256];
  __shared__ u64 sh_prefix;
  __shared__ int sh_k;
  __shared__ int sh_cnt;

  int b = blockIdx.x;
  int tid = threadIdx.x;
  int lane = tid & 63;

  for (int i = tid; i < NA; i += 1024) skeys[i] = keys[b * NA + i];
  if (tid == 0) { sh_prefix = 0; sh_k = CANDN; sh_cnt = 0; }
  __syncthreads();

  u64 prefix = 0;
  int k = CANDN;
  for (int shift = 56; shift >= 0; shift -= 8) {
    if (tid < 256) hist[tid] = 0;
    __syncthreads();
    u64 pmask = (shift == 56) ? 0ULL : (~0ULL << (shift + 8));
    for (int i = tid; i < NA_PAD; i += 1024) {
      bool act = false;
      int d = 0;
      if (i < NA) {
        u64 key = skeys[i];
        act = (key & pmask) == prefix;
        d = (int)((key >> shift) & 255);
      }
      // wave-aggregate same-digit counts (scores cluster -> few hot bins)
      u64 m = __ballot(act);
      if (m) {
#pragma unroll
        for (int bit = 0; bit < 8; ++bit) {
          u64 bb = __ballot((d >> bit) & 1);
          m &= ((d >> bit) & 1) ? bb : ~bb;
        }
        if (act && (m & ((1ULL << lane) - 1)) == 0ULL)
          atomicAdd(&hist[d], (int)__popcll(m));
      }
    }
    __syncthreads();
    // inclusive scan of 256 bins by wave 0 (4 bins/lane, shfl scan, no barriers)
    if (tid < 64) {
      int v0 = hist[tid * 4 + 0], v1 = hist[tid * 4 + 1];
      int v2 = hist[tid * 4 + 2], v3 = hist[tid * 4 + 3];
      int s0 = v0, s1 = s0 + v1, s2 = s1 + v2, s3 = s2 + v3;
      int tot = s3;
      for (int off = 1; off < 64; off <<= 1) {
        int t = __shfl_up(tot, off, 64);
        if (tid >= off) tot += t;
      }
      int base = tot - s3;  // exclusive prefix of this lane's 4-bin group
      cum[tid * 4 + 0] = base + s0;
      cum[tid * 4 + 1] = base + s1;
      cum[tid * 4 + 2] = base + s2;
      cum[tid * 4 + 3] = base + s3;
    }
    __syncthreads();
    if (tid < 256) {
      int c = cum[tid];
      int cprev = (tid == 0) ? 0 : cum[tid - 1];
      if (c >= k && cprev < k) {  // exactly one digit satisfies this
        sh_prefix = prefix | ((u64)tid << shift);
        sh_k = k - cprev;
      }
    }
    __syncthreads();
    prefix = sh_prefix;
    k = sh_k;
  }

  // prefix == exact 2048th-smallest key; keys distinct -> exactly 2048 pass
  for (int i = tid; i < NA_PAD; i += 1024) {
    bool act = false;
    u64 key = 0;
    if (i < NA) { key = skeys[i]; act = key <= prefix; }
    u64 mm = __ballot(act);
    if (mm) {
      int leader = __ffsll(mm) - 1;
      int base = 0;
      if (lane == leader) base = atomicAdd(&sh_cnt, (int)__popcll(mm));
      base = __shfl(base, leader, 64);
      if (act) sortbuf[base + (int)__popcll(mm & ((1ULL << lane) - 1))] = key;
    }
  }
  __syncthreads();

  // bitonic sort 2048 keys ascending, 1024 threads = 1 comparator each
  for (int kk = 2; kk <= CANDN; kk <<= 1) {
    for (int j = kk >> 1; j > 0; j >>= 1) {
      int low = tid & (j - 1);
      int i2 = ((tid ^ low) << 1) | low;
      int l = i2 | j;
      u64 a = sortbuf[i2];
      u64 c = sortbuf[l];
      bool asc = (i2 & kk) == 0;
      if ((a > c) == asc) { sortbuf[i2] = c; sortbuf[l] = a; }
      __syncthreads();
    }
  }

  for (int t = tid; t < CANDN; t += 1024) {
    u64 key = sortbuf[t];
    tidx[b * CANDN + t] = (int)(unsigned int)(key & 0xFFFFFFFFu);
    tsc[b * CANDN + t] = __uint_as_float(~(unsigned int)(key >> 32));
  }
}

// ---------- kernel 3: gather box, xyxy, nms-box, area, valid mask ----------
__global__ __launch_bounds__(256) void prep_kernel(const float* __restrict__ pred,
                                                   const int* __restrict__ tidx,
                                                   const float* __restrict__ tsc,
                                                   const int* __restrict__ cls,
                                                   const int* __restrict__ imgsz,
                                                   float* __restrict__ cand,
                                                   float4* __restrict__ nmsb,
                                                   float* __restrict__ area,
                                                   u64* __restrict__ vmask) {
  int k = blockIdx.x * 256 + threadIdx.x;
  int b = blockIdx.y;
  int o = b * CANDN + k;
  int idx = tidx[o];
  float score = tsc[o];
  const float* pb = pred + (size_t)b * (NCH * NA);
  float x = pb[0 * NA + idx];
  float y = pb[1 * NA + idx];
  float w = pb[2 * NA + idx];
  float h = pb[3 * NA + idx];
  float hw = __fmul_rn(w, 0.5f);
  float hh = __fmul_rn(h, 0.5f);
  float x1 = __fsub_rn(x, hw);
  float y1 = __fsub_rn(y, hh);
  float x2 = __fadd_rn(x, hw);
  float y2 = __fadd_rn(y, hh);
  float clsf = (float)cls[b * NA + idx];
  float inv = (float)(1.0 / (double)imgsz[0]);
  float nx1 = __fadd_rn(__fmul_rn(x1, inv), clsf);
  float ny1 = __fadd_rn(__fmul_rn(y1, inv), clsf);
  float nx2 = __fadd_rn(__fmul_rn(x2, inv), clsf);
  float ny2 = __fadd_rn(__fmul_rn(y2, inv), clsf);
  float ar = __fmul_rn(__fsub_rn(nx2, nx1), __fsub_rn(ny2, ny1));
  bool valid = score > 0.25f;
  cand[(size_t)o * 6 + 0] = x1;
  cand[(size_t)o * 6 + 1] = y1;
  cand[(size_t)o * 6 + 2] = x2;
  cand[(size_t)o * 6 + 3] = y2;
  cand[(size_t)o * 6 + 4] = score;
  cand[(size_t)o * 6 + 5] = clsf;
  nmsb[o] = make_float4(nx1, ny1, nx2, ny2);
  area[o] = ar;
  u64 bal = __ballot(valid);
  if ((threadIdx.x & 63) == 0) vmask[b * 32 + (k >> 6)] = bal;
}

// ---------- kernel 4: suppression bit-matrix M[i][word] ----------
__global__ __launch_bounds__(256) void iou_kernel(const float4* __restrict__ nmsb,
                                                  const float* __restrict__ area,
                                                  u64* __restrict__ M) {
  int i = blockIdx.x;
  int b = blockIdx.y;
  int wv = threadIdx.x >> 6;
  int lane = threadIdx.x & 63;
  int ob = b * CANDN;
  float4 bi = nmsb[ob + i];
  float ai = area[ob + i];
#pragma unroll
  for (int it = 0; it < 8; ++it) {
    int w = wv + it * 4;  // words 0..31
    int j = (w << 6) + lane;
    float4 bj = nmsb[ob + j];
    float aj = area[ob + j];
    float ix1 = fmaxf(bi.x, bj.x);
    float iy1 = fmaxf(bi.y, bj.y);
    float ix2 = fminf(bi.z, bj.z);
    float iy2 = fminf(bi.w, bj.w);
    float iw = fmaxf(__fsub_rn(ix2, ix1), 0.0f);
    float ih = fmaxf(__fsub_rn(iy2, iy1), 0.0f);
    float inter = __fmul_rn(iw, ih);
    float denom = __fadd_rn(__fsub_rn(__fadd_rn(ai, aj), inter), 1e-7f);
    float iou = __fdiv_rn(inter, denom);
    u64 bal = __ballot(iou > 0.45f);
    if (lane == 0) M[(((size_t)(ob + i)) << 5) + w] = bal;
  }
}

// ---------- kernel 5: chunked greedy scan, all state in registers ----------
// Key fact: IoU is symmetric => M is symmetric => row j == column j.
// Lane j of chunk c owns candidate g = c*64+j and holds M-row words 0..c in
// registers (chunk loop fully unrolled => static indexing). Cross-chunk
// suppression = OR_w<c (K[w] & mt[w]); intra-chunk greedy = ballot+ffs per
// keep, no shuffles, no memory on the serial chain.
__global__ __launch_bounds__(64) void scan_kernel(const u64* __restrict__ M,
                                                  const u64* __restrict__ vmaskg,
                                                  const float* __restrict__ cand,
                                                  float* __restrict__ out) {
  __shared__ int idxbuf[MAXDET];
  int b = blockIdx.x;
  int lane = threadIdx.x;
  const u64* Mb = M + (((size_t)b * CANDN) << 5);
  u64 K[32];
#pragma unroll
  for (int w = 0; w < 32; ++w) K[w] = 0ULL;
  u64 mt[32];
  int cnt = 0;
#pragma unroll 32
  for (int c = 0; c < 32; ++c) {
    if (cnt < MAXDET) {
      int jg = (c << 6) + lane;
      const int npairs = c / 2 + 1;  // row words 0..c (pair-granular over-read ok)
#pragma unroll
      for (int t = 0; t < npairs; ++t) {
        ulonglong2 v = *(const ulonglong2*)(Mb + ((size_t)jg << 5) + (t << 1));
        mt[2 * t] = v.x;
        mt[2 * t + 1] = v.y;
      }
      u64 vw = vmaskg[b * 32 + c];
      bool tent = ((vw >> lane) & 1ULL) != 0ULL;
      u64 acc = 0ULL;
#pragma unroll
      for (int w = 0; w < c; ++w) acc |= (K[w] & mt[w]);
      tent = tent && (acc == 0ULL);
      u64 col = mt[c];  // bit k = in-chunk candidate k suppresses me
      u64 keptloc = 0ULL;
      while (true) {
        bool alive = tent && ((keptloc & col) == 0ULL);
        u64 bal = __ballot(alive);
        if (bal == 0ULL) break;
        int f = __ffsll(bal) - 1;       // lowest alive index = next greedy keep
        keptloc |= (1ULL << f);
        tent = tent && (lane != f);     // self-clear (diagonal may be 0)
        if (lane == 0) idxbuf[cnt] = (c << 6) + f;
        cnt++;
        if (cnt >= MAXDET) break;
      }
      K[c] = keptloc;
    }
  }
  __syncthreads();
  int total = cnt;
  // parallel epilogue: gather kept rows, zero-fill the rest
  for (int r = lane; r < MAXDET; r += 64) {
    float vals[6] = {0.f, 0.f, 0.f, 0.f, 0.f, 0.f};
    if (r < total) {
      int g = idxbuf[r];
#pragma unroll
      for (int q = 0; q < 6; ++q)
        vals[q] = cand[((size_t)(b * CANDN) + g) * 6 + q];
    }
#pragma unroll
    for (int q = 0; q < 6; ++q)
      out[((size_t)(b * MAXDET) + r) * 6 + q] = vals[q];
  }
}

extern "C" void kernel_launch(void* const* d_in, const int* in_sizes, int n_in,
                              void* d_out, int out_size, void* d_ws, size_t ws_size,
                              hipStream_t stream) {
  (void)in_sizes; (void)n_in; (void)out_size; (void)ws_size;
  const float* pred = (const float*)d_in[0];
  const int* imgsz = (const int*)d_in[1];
  char* ws = (char*)d_ws;
  u64* keys = (u64*)(ws + OFF_KEYS);
  int* cls = (int*)(ws + OFF_CLS);
  int* tidx = (int*)(ws + OFF_TIDX);
  float* tsc = (float*)(ws + OFF_TSC);
  float* cand = (float*)(ws + OFF_CAND);
  float4* nmsb = (float4*)(ws + OFF_NMS);
  float* area = (float*)(ws + OFF_AREA);
  u64* vmask = (u64*)(ws + OFF_VAL);
  u64* M = (u64*)(ws + OFF_M);
  float* out = (float*)d_out;

  score_kernel<<<dim3((NA + 255) / 256, NB), 256, 0, stream>>>(pred, keys, cls);
  select_kernel<<<NB, 1024, 0, stream>>>(keys, tidx, tsc);
  prep_kernel<<<dim3(CANDN / 256, NB), 256, 0, stream>>>(pred, tidx, tsc, cls, imgsz,
                                                         cand, nmsb, area, vmask);
  iou_kernel<<<dim3(CANDN, NB), 256, 0, stream>>>(nmsb, area, M);
  scan_kernel<<<NB, 64, 0, stream>>>(M, vmask, cand, out);
}

// Round 5
// 134.993 us; speedup vs baseline: 1.8613x; 1.2220x over previous
//
#include <hip/hip_runtime.h>
#include <stdint.h>

#define NB 16
#define NA 8400
#define NA_PAD 9216
#define NCH 84
#define NCLS 80
#define CANDN 2048
#define MAXDET 300

typedef unsigned long long u64;

// ---------------- workspace layout (bytes) ----------------
static const size_t OFF_KEYS = 0;
static const size_t OFF_CLS  = 1075200;
static const size_t OFF_TIDX = 1612800;
static const size_t OFF_TSC  = 1743872;
static const size_t OFF_CAND = 1874944;
static const size_t OFF_NMS  = 2661376;
static const size_t OFF_AREA = 3185664;
static const size_t OFF_VAL  = 3316736;
static const size_t OFF_M    = 3320832;
// total ~11.7 MB

// ---------- kernel 1: per-anchor class max + argmax, build sort key ----------
__global__ __launch_bounds__(256) void score_kernel(const float* __restrict__ pred,
                                                    u64* __restrict__ keys,
                                                    int* __restrict__ cls) {
  int a = blockIdx.x * 256 + threadIdx.x;
  int b = blockIdx.y;
  if (a >= NA) return;
  const float* p = pred + (size_t)b * (NCH * NA) + 4 * NA + a;
  float best = p[0];
  int bc = 0;
#pragma unroll 8
  for (int c = 1; c < NCLS; ++c) {
    float v = p[(size_t)c * NA];
    if (v > best) { best = v; bc = c; }  // strict > : first-index argmax
  }
  // descending score, ascending index on ties, via ascending uint64 sort
  keys[b * NA + a] = (((u64)(~__float_as_uint(best))) << 32) | (unsigned int)a;
  cls[b * NA + a] = bc;
}

// ---------- kernel 2: radix-select top-2048 + bitonic sort of the 2048 ----------
__global__ __launch_bounds__(1024) void select_kernel(const u64* __restrict__ keys,
                                                      int* __restrict__ tidx,
                                                      float* __restrict__ tsc) {
  __shared__ u64 skeys[NA];       // 67200 B
  __shared__ u64 sortbuf[CANDN];  // 16384 B
  __shared__ int hist[256];
  __shared__ int cum[256];
  __shared__ u64 sh_prefix;
  __shared__ int sh_k;
  __shared__ int sh_cnt;

  int b = blockIdx.x;
  int tid = threadIdx.x;
  int lane = tid & 63;

  for (int i = tid; i < NA; i += 1024) skeys[i] = keys[b * NA + i];
  if (tid == 0) { sh_prefix = 0; sh_k = CANDN; sh_cnt = 0; }
  __syncthreads();

  u64 prefix = 0;
  int k = CANDN;
  for (int shift = 56; shift >= 0; shift -= 8) {
    if (tid < 256) hist[tid] = 0;
    __syncthreads();
    u64 pmask = (shift == 56) ? 0ULL : (~0ULL << (shift + 8));
    for (int i = tid; i < NA_PAD; i += 1024) {
      bool act = false;
      int d = 0;
      if (i < NA) {
        u64 key = skeys[i];
        act = (key & pmask) == prefix;
        d = (int)((key >> shift) & 255);
      }
      // wave-aggregate same-digit counts (scores cluster -> few hot bins)
      u64 m = __ballot(act);
      if (m) {
#pragma unroll
        for (int bit = 0; bit < 8; ++bit) {
          u64 bb = __ballot((d >> bit) & 1);
          m &= ((d >> bit) & 1) ? bb : ~bb;
        }
        if (act && (m & ((1ULL << lane) - 1)) == 0ULL)
          atomicAdd(&hist[d], (int)__popcll(m));
      }
    }
    __syncthreads();
    // inclusive scan of 256 bins by wave 0 (4 bins/lane, shfl scan, no barriers)
    if (tid < 64) {
      int v0 = hist[tid * 4 + 0], v1 = hist[tid * 4 + 1];
      int v2 = hist[tid * 4 + 2], v3 = hist[tid * 4 + 3];
      int s0 = v0, s1 = s0 + v1, s2 = s1 + v2, s3 = s2 + v3;
      int tot = s3;
      for (int off = 1; off < 64; off <<= 1) {
        int t = __shfl_up(tot, off, 64);
        if (tid >= off) tot += t;
      }
      int base = tot - s3;  // exclusive prefix of this lane's 4-bin group
      cum[tid * 4 + 0] = base + s0;
      cum[tid * 4 + 1] = base + s1;
      cum[tid * 4 + 2] = base + s2;
      cum[tid * 4 + 3] = base + s3;
    }
    __syncthreads();
    if (tid < 256) {
      int c = cum[tid];
      int cprev = (tid == 0) ? 0 : cum[tid - 1];
      if (c >= k && cprev < k) {  // exactly one digit satisfies this
        sh_prefix = prefix | ((u64)tid << shift);
        sh_k = k - cprev;
      }
    }
    __syncthreads();
    prefix = sh_prefix;
    k = sh_k;
  }

  // prefix == exact 2048th-smallest key; keys distinct -> exactly 2048 pass
  for (int i = tid; i < NA_PAD; i += 1024) {
    bool act = false;
    u64 key = 0;
    if (i < NA) { key = skeys[i]; act = key <= prefix; }
    u64 mm = __ballot(act);
    if (mm) {
      int leader = __ffsll(mm) - 1;
      int base = 0;
      if (lane == leader) base = atomicAdd(&sh_cnt, (int)__popcll(mm));
      base = __shfl(base, leader, 64);
      if (act) sortbuf[base + (int)__popcll(mm & ((1ULL << lane) - 1))] = key;
    }
  }
  __syncthreads();

  // bitonic sort 2048 keys ascending, 1024 threads = 1 comparator each
  for (int kk = 2; kk <= CANDN; kk <<= 1) {
    for (int j = kk >> 1; j > 0; j >>= 1) {
      int low = tid & (j - 1);
      int i2 = ((tid ^ low) << 1) | low;
      int l = i2 | j;
      u64 a = sortbuf[i2];
      u64 c = sortbuf[l];
      bool asc = (i2 & kk) == 0;
      if ((a > c) == asc) { sortbuf[i2] = c; sortbuf[l] = a; }
      __syncthreads();
    }
  }

  for (int t = tid; t < CANDN; t += 1024) {
    u64 key = sortbuf[t];
    tidx[b * CANDN + t] = (int)(unsigned int)(key & 0xFFFFFFFFu);
    tsc[b * CANDN + t] = __uint_as_float(~(unsigned int)(key >> 32));
  }
}

// ---------- kernel 3: gather box, xyxy, nms-box, area, valid mask ----------
__global__ __launch_bounds__(256) void prep_kernel(const float* __restrict__ pred,
                                                   const int* __restrict__ tidx,
                                                   const float* __restrict__ tsc,
                                                   const int* __restrict__ cls,
                                                   const int* __restrict__ imgsz,
                                                   float* __restrict__ cand,
                                                   float4* __restrict__ nmsb,
                                                   float* __restrict__ area,
                                                   u64* __restrict__ vmask) {
  int k = blockIdx.x * 256 + threadIdx.x;
  int b = blockIdx.y;
  int o = b * CANDN + k;
  int idx = tidx[o];
  float score = tsc[o];
  const float* pb = pred + (size_t)b * (NCH * NA);
  float x = pb[0 * NA + idx];
  float y = pb[1 * NA + idx];
  float w = pb[2 * NA + idx];
  float h = pb[3 * NA + idx];
  float hw = __fmul_rn(w, 0.5f);
  float hh = __fmul_rn(h, 0.5f);
  float x1 = __fsub_rn(x, hw);
  float y1 = __fsub_rn(y, hh);
  float x2 = __fadd_rn(x, hw);
  float y2 = __fadd_rn(y, hh);
  float clsf = (float)cls[b * NA + idx];
  float inv = (float)(1.0 / (double)imgsz[0]);
  float nx1 = __fadd_rn(__fmul_rn(x1, inv), clsf);
  float ny1 = __fadd_rn(__fmul_rn(y1, inv), clsf);
  float nx2 = __fadd_rn(__fmul_rn(x2, inv), clsf);
  float ny2 = __fadd_rn(__fmul_rn(y2, inv), clsf);
  float ar = __fmul_rn(__fsub_rn(nx2, nx1), __fsub_rn(ny2, ny1));
  bool valid = score > 0.25f;
  cand[(size_t)o * 6 + 0] = x1;
  cand[(size_t)o * 6 + 1] = y1;
  cand[(size_t)o * 6 + 2] = x2;
  cand[(size_t)o * 6 + 3] = y2;
  cand[(size_t)o * 6 + 4] = score;
  cand[(size_t)o * 6 + 5] = clsf;
  nmsb[o] = make_float4(nx1, ny1, nx2, ny2);
  area[o] = ar;
  u64 bal = __ballot(valid);
  if ((threadIdx.x & 63) == 0) vmask[b * 32 + (k >> 6)] = bal;
}

// ---------- kernel 4: suppression bit-matrix, block-lower-triangle only ----------
// Scan consumes row j (chunk c) words 0..c only (M symmetric), so compute
// only w <= i>>6 : 51.6% of the pairs. Division eliminated exactly:
// fl32(inter/denom) > 0.45f  <=>  inter/denom > 0.45f + 2^-26 (tie rounds to
// even = 0.45f itself), and with denom>0 this is (double)inter > THR*(double)denom,
// where the f64 product of a 25-bit and a 24-bit value is exact.
__global__ __launch_bounds__(256) void iou_kernel(const float4* __restrict__ nmsb,
                                                  const float* __restrict__ area,
                                                  u64* __restrict__ M) {
  int i = blockIdx.x;
  int b = blockIdx.y;
  int c = i >> 6;  // chunk of row i; only words 0..c are ever read by scan
  int wv = threadIdx.x >> 6;
  int lane = threadIdx.x & 63;
  int ob = b * CANDN;
  float4 bi = nmsb[ob + i];
  float ai = area[ob + i];
  const double THR = 0x1.CCCCCC8p-2;  // 0.45f + 2^-26 exactly
  for (int w = wv; w <= c; w += 4) {
    int j = (w << 6) + lane;
    float4 bj = nmsb[ob + j];
    float aj = area[ob + j];
    float ix1 = fmaxf(bi.x, bj.x);
    float iy1 = fmaxf(bi.y, bj.y);
    float ix2 = fminf(bi.z, bj.z);
    float iy2 = fminf(bi.w, bj.w);
    float iw = fmaxf(__fsub_rn(ix2, ix1), 0.0f);
    float ih = fmaxf(__fsub_rn(iy2, iy1), 0.0f);
    float inter = __fmul_rn(iw, ih);
    float denom = __fadd_rn(__fsub_rn(__fadd_rn(ai, aj), inter), 1e-7f);
    bool sup = (double)inter > THR * (double)denom;
    u64 bal = __ballot(sup);
    if (lane == 0) M[(((size_t)(ob + i)) << 5) + w] = bal;
  }
}

// ---------- kernel 5: chunked greedy scan, all state in registers ----------
// Key fact: IoU is symmetric => M is symmetric => row j == column j.
// Lane j of chunk c owns candidate g = c*64+j and holds M-row words 0..c in
// registers (chunk loop fully unrolled => static indexing). Cross-chunk
// suppression = OR_w<c (K[w] & mt[w]); intra-chunk greedy = ballot+ffs per
// keep, no shuffles, no memory on the serial chain.
__global__ __launch_bounds__(64) void scan_kernel(const u64* __restrict__ M,
                                                  const u64* __restrict__ vmaskg,
                                                  const float* __restrict__ cand,
                                                  float* __restrict__ out) {
  __shared__ int idxbuf[MAXDET];
  int b = blockIdx.x;
  int lane = threadIdx.x;
  const u64* Mb = M + (((size_t)b * CANDN) << 5);
  u64 K[32];
#pragma unroll
  for (int w = 0; w < 32; ++w) K[w] = 0ULL;
  u64 mt[32];
  int cnt = 0;
#pragma unroll 32
  for (int c = 0; c < 32; ++c) {
    if (cnt < MAXDET) {
      int jg = (c << 6) + lane;
      const int npairs = c / 2 + 1;  // row words 0..c (pair-granular over-read ok)
#pragma unroll
      for (int t = 0; t < npairs; ++t) {
        ulonglong2 v = *(const ulonglong2*)(Mb + ((size_t)jg << 5) + (t << 1));
        mt[2 * t] = v.x;
        mt[2 * t + 1] = v.y;
      }
      u64 vw = vmaskg[b * 32 + c];
      bool tent = ((vw >> lane) & 1ULL) != 0ULL;
      u64 acc = 0ULL;
#pragma unroll
      for (int w = 0; w < c; ++w) acc |= (K[w] & mt[w]);
      tent = tent && (acc == 0ULL);
      u64 col = mt[c];  // bit k = in-chunk candidate k suppresses me
      u64 keptloc = 0ULL;
      while (true) {
        bool alive = tent && ((keptloc & col) == 0ULL);
        u64 bal = __ballot(alive);
        if (bal == 0ULL) break;
        int f = __ffsll(bal) - 1;       // lowest alive index = next greedy keep
        keptloc |= (1ULL << f);
        tent = tent && (lane != f);     // self-clear (diagonal may be 0)
        if (lane == 0) idxbuf[cnt] = (c << 6) + f;
        cnt++;
        if (cnt >= MAXDET) break;
      }
      K[c] = keptloc;
    }
  }
  __syncthreads();
  int total = cnt;
  // parallel epilogue: gather kept rows, zero-fill the rest
  for (int r = lane; r < MAXDET; r += 64) {
    float vals[6] = {0.f, 0.f, 0.f, 0.f, 0.f, 0.f};
    if (r < total) {
      int g = idxbuf[r];
#pragma unroll
      for (int q = 0; q < 6; ++q)
        vals[q] = cand[((size_t)(b * CANDN) + g) * 6 + q];
    }
#pragma unroll
    for (int q = 0; q < 6; ++q)
      out[((size_t)(b * MAXDET) + r) * 6 + q] = vals[q];
  }
}

extern "C" void kernel_launch(void* const* d_in, const int* in_sizes, int n_in,
                              void* d_out, int out_size, void* d_ws, size_t ws_size,
                              hipStream_t stream) {
  (void)in_sizes; (void)n_in; (void)out_size; (void)ws_size;
  const float* pred = (const float*)d_in[0];
  const int* imgsz = (const int*)d_in[1];
  char* ws = (char*)d_ws;
  u64* keys = (u64*)(ws + OFF_KEYS);
  int* cls = (int*)(ws + OFF_CLS);
  int* tidx = (int*)(ws + OFF_TIDX);
  float* tsc = (float*)(ws + OFF_TSC);
  float* cand = (float*)(ws + OFF_CAND);
  float4* nmsb = (float4*)(ws + OFF_NMS);
  float* area = (float*)(ws + OFF_AREA);
  u64* vmask = (u64*)(ws + OFF_VAL);
  u64* M = (u64*)(ws + OFF_M);
  float* out = (float*)d_out;

  score_kernel<<<dim3((NA + 255) / 256, NB), 256, 0, stream>>>(pred, keys, cls);
  select_kernel<<<NB, 1024, 0, stream>>>(keys, tidx, tsc);
  prep_kernel<<<dim3(CANDN / 256, NB), 256, 0, stream>>>(pred, tidx, tsc, cls, imgsz,
                                                         cand, nmsb, area, vmask);
  iou_kernel<<<dim3(CANDN, NB), 256, 0, stream>>>(nmsb, area, M);
  scan_kernel<<<NB, 64, 0, stream>>>(M, vmask, cand, out);
}

// Round 6
// 134.844 us; speedup vs baseline: 1.8634x; 1.0011x over previous
//
#include <hip/hip_runtime.h>
#include <stdint.h>

#define NB 16
#define NA 8400
#define NA_PAD 9216
#define NCH 84
#define NCLS 80
#define CANDN 2048
#define MAXDET 300

typedef unsigned long long u64;

// ---------------- workspace layout (bytes) ----------------
static const size_t OFF_KEYS = 0;
static const size_t OFF_CLS  = 1075200;
static const size_t OFF_TIDX = 1612800;
static const size_t OFF_TSC  = 1743872;
static const size_t OFF_CAND = 1874944;
static const size_t OFF_NMS  = 2661376;
static const size_t OFF_AREA = 3185664;
static const size_t OFF_VAL  = 3316736;
static const size_t OFF_M    = 3320832;
// total ~11.7 MB

// ---------- kernel 1: per-anchor class max + argmax, build sort key ----------
__global__ __launch_bounds__(256) void score_kernel(const float* __restrict__ pred,
                                                    u64* __restrict__ keys,
                                                    int* __restrict__ cls) {
  int a = blockIdx.x * 256 + threadIdx.x;
  int b = blockIdx.y;
  if (a >= NA) return;
  const float* p = pred + (size_t)b * (NCH * NA) + 4 * NA + a;
  float best = p[0];
  int bc = 0;
#pragma unroll 8
  for (int c = 1; c < NCLS; ++c) {
    float v = p[(size_t)c * NA];
    if (v > best) { best = v; bc = c; }  // strict > : first-index argmax
  }
  // descending score, ascending index on ties, via ascending uint64 sort
  keys[b * NA + a] = (((u64)(~__float_as_uint(best))) << 32) | (unsigned int)a;
  cls[b * NA + a] = bc;
}

__device__ inline u64 shflx64(u64 v, int m) {
  int lo = __shfl_xor((int)(unsigned)(v & 0xFFFFFFFFu), m, 64);
  int hi = __shfl_xor((int)(unsigned)(v >> 32), m, 64);
  return (((u64)(unsigned)hi) << 32) | (unsigned)lo;
}

// bitonic compare-exchange result for the element at slot s
__device__ inline u64 cswap(u64 a, u64 b, int s, int j, int kk) {
  bool low = (s & j) == 0;
  bool asc = (s & kk) == 0;
  bool takeMin = (low == asc);
  u64 mn = (a < b) ? a : b;
  u64 mx = (a < b) ? b : a;
  return takeMin ? mn : mx;
}

// ---------- kernel 2: 4-pass radix-select on score bits + hybrid bitonic ----------
__global__ __launch_bounds__(1024) void select_kernel(const u64* __restrict__ keys,
                                                      int* __restrict__ tidx,
                                                      float* __restrict__ tsc) {
  __shared__ u64 skeys[NA];       // 67200 B
  __shared__ u64 sortbuf[CANDN];  // 16384 B
  __shared__ int hist[256];
  __shared__ int cum[256];
  __shared__ int tielist[1024];   // 4096 B
  __shared__ unsigned int sh_prefix;
  __shared__ int sh_k;
  __shared__ int sh_g;
  __shared__ int sh_cnt;

  int b = blockIdx.x;
  int tid = threadIdx.x;
  int lane = tid & 63;

  for (int i = tid; i < NA; i += 1024) skeys[i] = keys[b * NA + i];
  if (tid == 0) { sh_prefix = 0; sh_k = CANDN; sh_g = 0; sh_cnt = 0; }
  __syncthreads();

  // ---- 4-pass radix select on u = key>>32 (score part only) ----
  unsigned prefix = 0;
  int k = CANDN;
  for (int shift = 24; shift >= 0; shift -= 8) {
    if (tid < 256) hist[tid] = 0;
    __syncthreads();
    unsigned pmask = (shift == 24) ? 0u : (0xFFFFFFFFu << (shift + 8));
    for (int i = tid; i < NA_PAD; i += 1024) {
      bool act = false;
      int d = 0;
      if (i < NA) {
        unsigned u = (unsigned)(skeys[i] >> 32);
        act = (u & pmask) == prefix;
        d = (int)((u >> shift) & 255);
      }
      // wave-aggregate same-digit counts (scores cluster -> few hot bins)
      u64 m = __ballot(act);
      if (m) {
#pragma unroll
        for (int bit = 0; bit < 8; ++bit) {
          u64 bb = __ballot((d >> bit) & 1);
          m &= ((d >> bit) & 1) ? bb : ~bb;
        }
        if (act && (m & ((1ULL << lane) - 1)) == 0ULL)
          atomicAdd(&hist[d], (int)__popcll(m));
      }
    }
    __syncthreads();
    // inclusive scan of 256 bins by wave 0 (4 bins/lane, shfl scan)
    if (tid < 64) {
      int v0 = hist[tid * 4 + 0], v1 = hist[tid * 4 + 1];
      int v2 = hist[tid * 4 + 2], v3 = hist[tid * 4 + 3];
      int s0 = v0, s1 = s0 + v1, s2 = s1 + v2, s3 = s2 + v3;
      int tot = s3;
      for (int off = 1; off < 64; off <<= 1) {
        int t = __shfl_up(tot, off, 64);
        if (tid >= off) tot += t;
      }
      int base = tot - s3;
      cum[tid * 4 + 0] = base + s0;
      cum[tid * 4 + 1] = base + s1;
      cum[tid * 4 + 2] = base + s2;
      cum[tid * 4 + 3] = base + s3;
    }
    __syncthreads();
    if (tid < 256) {
      int c = cum[tid];
      int cprev = (tid == 0) ? 0 : cum[tid - 1];
      if (c >= k && cprev < k) {
        sh_prefix = prefix | ((unsigned)tid << shift);
        sh_k = k - cprev;
      }
    }
    __syncthreads();
    prefix = sh_prefix;
    k = sh_k;
  }
  unsigned ustar = prefix;  // exact score-bits of the 2048th-smallest
  int kp = k;               // how many to take from the u==ustar group

  // ---- boundary-group tie-fix by index rank ----
  for (int i = tid; i < NA; i += 1024) {
    unsigned u = (unsigned)(skeys[i] >> 32);
    if (u == ustar) {
      int p = atomicAdd(&sh_g, 1);
      if (p < 1024) tielist[p] = i;  // low 32 bits of key == slot index i
    }
  }
  __syncthreads();
  int g = sh_g < 1024 ? sh_g : 1024;

  // ---- compaction (unstable; sort below uses full 64-bit keys) ----
  for (int i = tid; i < NA_PAD; i += 1024) {
    bool act = false;
    u64 key = 0;
    if (i < NA) {
      key = skeys[i];
      unsigned u = (unsigned)(key >> 32);
      if (u < ustar) act = true;
      else if (u == ustar) {
        int r = 0;
        for (int t2 = 0; t2 < g; ++t2) r += (tielist[t2] < i);
        act = (r < kp);  // kp smallest indices within the boundary group
      }
    }
    u64 mm = __ballot(act);
    if (mm) {
      int leader = __ffsll(mm) - 1;
      int base = 0;
      if (lane == leader) base = atomicAdd(&sh_cnt, (int)__popcll(mm));
      base = __shfl(base, leader, 64);
      if (act) sortbuf[base + (int)__popcll(mm & ((1ULL << lane) - 1))] = key;
    }
  }
  __syncthreads();

  // ---- hybrid bitonic sort of 2048 u64 keys ----
  // thread t holds slots t and t+1024 in registers; j<64 via shfl (no barrier),
  // j==1024 via register pair, only j in {64,128,256,512} via LDS.
  u64 e0 = sortbuf[tid];
  u64 e1 = sortbuf[tid + 1024];
  for (int kk = 2; kk <= CANDN; kk <<= 1) {
    for (int j = kk >> 1; j > 0; j >>= 1) {
      if (j == 1024) {  // partner of slot t is t+1024: both in-register
        u64 mn = (e0 < e1) ? e0 : e1;
        u64 mx = (e0 < e1) ? e1 : e0;
        e0 = mn; e1 = mx;  // kk==2048: ascending everywhere
      } else if (j >= 64) {
        sortbuf[tid] = e0;
        sortbuf[tid + 1024] = e1;
        __syncthreads();
        u64 p0 = sortbuf[tid ^ j];
        u64 p1 = sortbuf[(tid + 1024) ^ j];
        e0 = cswap(e0, p0, tid, j, kk);
        e1 = cswap(e1, p1, tid + 1024, j, kk);
        __syncthreads();
      } else {
        u64 p0 = shflx64(e0, j);
        u64 p1 = shflx64(e1, j);
        e0 = cswap(e0, p0, tid, j, kk);
        e1 = cswap(e1, p1, tid + 1024, j, kk);
      }
    }
  }

  tidx[b * CANDN + tid] = (int)(unsigned)(e0 & 0xFFFFFFFFu);
  tsc[b * CANDN + tid] = __uint_as_float(~(unsigned)(e0 >> 32));
  tidx[b * CANDN + tid + 1024] = (int)(unsigned)(e1 & 0xFFFFFFFFu);
  tsc[b * CANDN + tid + 1024] = __uint_as_float(~(unsigned)(e1 >> 32));
}

// ---------- kernel 3: gather box, xyxy, nms-box, area, valid mask ----------
__global__ __launch_bounds__(256) void prep_kernel(const float* __restrict__ pred,
                                                   const int* __restrict__ tidx,
                                                   const float* __restrict__ tsc,
                                                   const int* __restrict__ cls,
                                                   const int* __restrict__ imgsz,
                                                   float* __restrict__ cand,
                                                   float4* __restrict__ nmsb,
                                                   float* __restrict__ area,
                                                   u64* __restrict__ vmask) {
  int k = blockIdx.x * 256 + threadIdx.x;
  int b = blockIdx.y;
  int o = b * CANDN + k;
  int idx = tidx[o];
  float score = tsc[o];
  const float* pb = pred + (size_t)b * (NCH * NA);
  float x = pb[0 * NA + idx];
  float y = pb[1 * NA + idx];
  float w = pb[2 * NA + idx];
  float h = pb[3 * NA + idx];
  float hw = __fmul_rn(w, 0.5f);
  float hh = __fmul_rn(h, 0.5f);
  float x1 = __fsub_rn(x, hw);
  float y1 = __fsub_rn(y, hh);
  float x2 = __fadd_rn(x, hw);
  float y2 = __fadd_rn(y, hh);
  float clsf = (float)cls[b * NA + idx];
  float inv = (float)(1.0 / (double)imgsz[0]);
  float nx1 = __fadd_rn(__fmul_rn(x1, inv), clsf);
  float ny1 = __fadd_rn(__fmul_rn(y1, inv), clsf);
  float nx2 = __fadd_rn(__fmul_rn(x2, inv), clsf);
  float ny2 = __fadd_rn(__fmul_rn(y2, inv), clsf);
  float ar = __fmul_rn(__fsub_rn(nx2, nx1), __fsub_rn(ny2, ny1));
  bool valid = score > 0.25f;
  cand[(size_t)o * 6 + 0] = x1;
  cand[(size_t)o * 6 + 1] = y1;
  cand[(size_t)o * 6 + 2] = x2;
  cand[(size_t)o * 6 + 3] = y2;
  cand[(size_t)o * 6 + 4] = score;
  cand[(size_t)o * 6 + 5] = clsf;
  nmsb[o] = make_float4(nx1, ny1, nx2, ny2);
  area[o] = ar;
  u64 bal = __ballot(valid);
  if ((threadIdx.x & 63) == 0) vmask[b * 32 + (k >> 6)] = bal;
}

// ---------- kernel 4: suppression bit-matrix, block-lower-triangle only ----------
__global__ __launch_bounds__(256) void iou_kernel(const float4* __restrict__ nmsb,
                                                  const float* __restrict__ area,
                                                  u64* __restrict__ M) {
  int i = blockIdx.x;
  int b = blockIdx.y;
  int c = i >> 6;  // chunk of row i; only words 0..c are ever read by scan
  int wv = threadIdx.x >> 6;
  int lane = threadIdx.x & 63;
  int ob = b * CANDN;
  float4 bi = nmsb[ob + i];
  float ai = area[ob + i];
  const double THR = 0x1.CCCCCC8p-2;  // 0.45f + 2^-26 exactly
  for (int w = wv; w <= c; w += 4) {
    int j = (w << 6) + lane;
    float4 bj = nmsb[ob + j];
    float aj = area[ob + j];
    float ix1 = fmaxf(bi.x, bj.x);
    float iy1 = fmaxf(bi.y, bj.y);
    float ix2 = fminf(bi.z, bj.z);
    float iy2 = fminf(bi.w, bj.w);
    float iw = fmaxf(__fsub_rn(ix2, ix1), 0.0f);
    float ih = fmaxf(__fsub_rn(iy2, iy1), 0.0f);
    float inter = __fmul_rn(iw, ih);
    float denom = __fadd_rn(__fsub_rn(__fadd_rn(ai, aj), inter), 1e-7f);
    bool sup = (double)inter > THR * (double)denom;
    u64 bal = __ballot(sup);
    if (lane == 0) M[(((size_t)(ob + i)) << 5) + w] = bal;
  }
}

// ---------- kernel 5: chunked greedy scan, all state in registers ----------
__global__ __launch_bounds__(64) void scan_kernel(const u64* __restrict__ M,
                                                  const u64* __restrict__ vmaskg,
                                                  const float* __restrict__ cand,
                                                  float* __restrict__ out) {
  __shared__ int idxbuf[MAXDET];
  int b = blockIdx.x;
  int lane = threadIdx.x;
  const u64* Mb = M + (((size_t)b * CANDN) << 5);
  u64 K[32];
#pragma unroll
  for (int w = 0; w < 32; ++w) K[w] = 0ULL;
  u64 mt[32];
  int cnt = 0;
#pragma unroll 32
  for (int c = 0; c < 32; ++c) {
    if (cnt < MAXDET) {
      int jg = (c << 6) + lane;
      const int npairs = c / 2 + 1;  // row words 0..c (pair-granular over-read ok)
#pragma unroll
      for (int t = 0; t < npairs; ++t) {
        ulonglong2 v = *(const ulonglong2*)(Mb + ((size_t)jg << 5) + (t << 1));
        mt[2 * t] = v.x;
        mt[2 * t + 1] = v.y;
      }
      u64 vw = vmaskg[b * 32 + c];
      bool tent = ((vw >> lane) & 1ULL) != 0ULL;
      u64 acc = 0ULL;
#pragma unroll
      for (int w = 0; w < c; ++w) acc |= (K[w] & mt[w]);
      tent = tent && (acc == 0ULL);
      u64 col = mt[c];  // bit k = in-chunk candidate k suppresses me
      u64 keptloc = 0ULL;
      while (true) {
        bool alive = tent && ((keptloc & col) == 0ULL);
        u64 bal = __ballot(alive);
        if (bal == 0ULL) break;
        int f = __ffsll(bal) - 1;       // lowest alive index = next greedy keep
        keptloc |= (1ULL << f);
        tent = tent && (lane != f);     // self-clear (diagonal may be 0)
        if (lane == 0) idxbuf[cnt] = (c << 6) + f;
        cnt++;
        if (cnt >= MAXDET) break;
      }
      K[c] = keptloc;
    }
  }
  __syncthreads();
  int total = cnt;
  // parallel epilogue: gather kept rows, zero-fill the rest
  for (int r = lane; r < MAXDET; r += 64) {
    float vals[6] = {0.f, 0.f, 0.f, 0.f, 0.f, 0.f};
    if (r < total) {
      int g = idxbuf[r];
#pragma unroll
      for (int q = 0; q < 6; ++q)
        vals[q] = cand[((size_t)(b * CANDN) + g) * 6 + q];
    }
#pragma unroll
    for (int q = 0; q < 6; ++q)
      out[((size_t)(b * MAXDET) + r) * 6 + q] = vals[q];
  }
}

extern "C" void kernel_launch(void* const* d_in, const int* in_sizes, int n_in,
                              void* d_out, int out_size, void* d_ws, size_t ws_size,
                              hipStream_t stream) {
  (void)in_sizes; (void)n_in; (void)out_size; (void)ws_size;
  const float* pred = (const float*)d_in[0];
  const int* imgsz = (const int*)d_in[1];
  char* ws = (char*)d_ws;
  u64* keys = (u64*)(ws + OFF_KEYS);
  int* cls = (int*)(ws + OFF_CLS);
  int* tidx = (int*)(ws + OFF_TIDX);
  float* tsc = (float*)(ws + OFF_TSC);
  float* cand = (float*)(ws + OFF_CAND);
  float4* nmsb = (float4*)(ws + OFF_NMS);
  float* area = (float*)(ws + OFF_AREA);
  u64* vmask = (u64*)(ws + OFF_VAL);
  u64* M = (u64*)(ws + OFF_M);
  float* out = (float*)d_out;

  score_kernel<<<dim3((NA + 255) / 256, NB), 256, 0, stream>>>(pred, keys, cls);
  select_kernel<<<NB, 1024, 0, stream>>>(keys, tidx, tsc);
  prep_kernel<<<dim3(CANDN / 256, NB), 256, 0, stream>>>(pred, tidx, tsc, cls, imgsz,
                                                         cand, nmsb, area, vmask);
  iou_kernel<<<dim3(CANDN, NB), 256, 0, stream>>>(nmsb, area, M);
  scan_kernel<<<NB, 64, 0, stream>>>(M, vmask, cand, out);
}

// Round 7
// 111.138 us; speedup vs baseline: 2.2609x; 1.2133x over previous
//
#include <hip/hip_runtime.h>
#include <stdint.h>

#define NB 16
#define NA 8400
#define NA_PAD 9216
#define NCH 84
#define NCLS 80
#define CANDN 2048
#define MAXDET 300

typedef unsigned long long u64;

// ---------------- workspace layout (bytes) ----------------
static const size_t OFF_KEYS = 0;        // 16*8400*8 = 1075200
static const size_t OFF_CLS  = 1075200;  // 16*8400*4 = 537600

// ---------- kernel 1: per-anchor class max + argmax, build sort key ----------
__global__ __launch_bounds__(256) void score_kernel(const float* __restrict__ pred,
                                                    u64* __restrict__ keys,
                                                    int* __restrict__ cls) {
  int a = blockIdx.x * 256 + threadIdx.x;
  int b = blockIdx.y;
  if (a >= NA) return;
  const float* p = pred + (size_t)b * (NCH * NA) + 4 * NA + a;
  float best = p[0];
  int bc = 0;
#pragma unroll 8
  for (int c = 1; c < NCLS; ++c) {
    float v = p[(size_t)c * NA];
    if (v > best) { best = v; bc = c; }  // strict > : first-index argmax
  }
  // descending score, ascending index on ties, via ascending uint64 sort
  keys[b * NA + a] = (((u64)(~__float_as_uint(best))) << 32) | (unsigned int)a;
  cls[b * NA + a] = bc;
}

__device__ inline u64 shflx64(u64 v, int m) {
  int lo = __shfl_xor((int)(unsigned)(v & 0xFFFFFFFFu), m, 64);
  int hi = __shfl_xor((int)(unsigned)(v >> 32), m, 64);
  return (((u64)(unsigned)hi) << 32) | (unsigned)lo;
}

__device__ inline u64 cswap(u64 a, u64 b, int s, int j, int kk) {
  bool low = (s & j) == 0;
  bool asc = (s & kk) == 0;
  bool takeMin = (low == asc);
  u64 mn = (a < b) ? a : b;
  u64 mx = (a < b) ? b : a;
  return takeMin ? mn : mx;
}

// ---------- kernel 2: fused select + sort + prep + lazy-IoU NMS + output ----------
// One block per image. Phases:
//  1. global->LDS load fused with radix pass-0 histogram; 3 more 8-bit passes.
//  2. boundary tie-fix by index rank; wave-aggregated compaction.
//  3. hybrid bitonic sort of 2048 (regs + shfl; LDS only for j in {64..512}).
//  4. prep: nmsb/area/sortedkey -> LDS (sA reused), valid ballot -> vmask.
//  5. chunked NMS: per chunk, 16 waves compute needed M words into LDS
//     (transposed [w][64] u64 -> stride-8B conflict-free reads), wave 0 scans.
//     Early exit at 300 keeps: ~99% of IoUs never computed.
//  6. output: re-gather pred by kept index, recompute box with identical
//     rounding ops (bit-exact), zero-fill rest.
__global__ __launch_bounds__(1024) void fused_kernel(const u64* __restrict__ keys,
                                                     const int* __restrict__ clsg,
                                                     const float* __restrict__ pred,
                                                     const int* __restrict__ imgsz,
                                                     float* __restrict__ out) {
  __shared__ alignas(16) u64 sA[NA];     // 67200 B: skeys; later nmsb/area/skey2/idxbuf
  __shared__ alignas(16) u64 sB[CANDN];  // 16384 B: sortbuf; later Mrows[32][64]
  __shared__ int hist[256];
  __shared__ int cum[256];
  __shared__ int tielist[1024];
  __shared__ u64 K_lds[32];
  __shared__ u64 vmask[32];
  __shared__ unsigned sh_prefix;
  __shared__ int sh_k, sh_g, sh_cnt, sh_nms;

  int b = blockIdx.x;
  int tid = threadIdx.x;
  int lane = tid & 63;
  int wv = tid >> 6;

  if (tid == 0) { sh_prefix = 0; sh_k = CANDN; sh_g = 0; sh_cnt = 0; sh_nms = 0; }
  if (tid < 32) K_lds[tid] = 0ULL;

  // ---- phase 1: 4-pass radix select on u = key>>32 (pass 0 fused with load) ----
  unsigned prefix = 0;
  int k = CANDN;
  for (int shift = 24; shift >= 0; shift -= 8) {
    if (tid < 256) hist[tid] = 0;
    __syncthreads();
    unsigned pmask = (shift == 24) ? 0u : (0xFFFFFFFFu << (shift + 8));
    for (int i = tid; i < NA_PAD; i += 1024) {
      bool act = false;
      int d = 0;
      if (i < NA) {
        u64 key;
        if (shift == 24) {
          key = keys[(size_t)b * NA + i];
          sA[i] = key;
          act = true;
        } else {
          key = sA[i];
          act = (((unsigned)(key >> 32)) & pmask) == prefix;
        }
        d = (int)((((unsigned)(key >> 32)) >> shift) & 255);
      }
      // wave-aggregate same-digit counts (scores cluster -> few hot bins)
      u64 m = __ballot(act);
      if (m) {
#pragma unroll
        for (int bit = 0; bit < 8; ++bit) {
          u64 bb = __ballot((d >> bit) & 1);
          m &= ((d >> bit) & 1) ? bb : ~bb;
        }
        if (act && (m & ((1ULL << lane) - 1)) == 0ULL)
          atomicAdd(&hist[d], (int)__popcll(m));
      }
    }
    __syncthreads();
    if (tid < 64) {  // inclusive scan of 256 bins by wave 0
      int v0 = hist[tid * 4 + 0], v1 = hist[tid * 4 + 1];
      int v2 = hist[tid * 4 + 2], v3 = hist[tid * 4 + 3];
      int s0 = v0, s1 = s0 + v1, s2 = s1 + v2, s3 = s2 + v3;
      int tot = s3;
      for (int off = 1; off < 64; off <<= 1) {
        int t = __shfl_up(tot, off, 64);
        if (tid >= off) tot += t;
      }
      int base = tot - s3;
      cum[tid * 4 + 0] = base + s0;
      cum[tid * 4 + 1] = base + s1;
      cum[tid * 4 + 2] = base + s2;
      cum[tid * 4 + 3] = base + s3;
    }
    __syncthreads();
    if (tid < 256) {
      int c = cum[tid];
      int cprev = (tid == 0) ? 0 : cum[tid - 1];
      if (c >= k && cprev < k) {
        sh_prefix = prefix | ((unsigned)tid << shift);
        sh_k = k - cprev;
      }
    }
    __syncthreads();
    prefix = sh_prefix;
    k = sh_k;
  }
  unsigned ustar = prefix;
  int kp = k;

  // ---- phase 2: boundary tie-fix + compaction ----
  for (int i = tid; i < NA; i += 1024) {
    unsigned u = (unsigned)(sA[i] >> 32);
    if (u == ustar) {
      int p = atomicAdd(&sh_g, 1);
      if (p < 1024) tielist[p] = i;
    }
  }
  __syncthreads();
  int g = sh_g < 1024 ? sh_g : 1024;

  for (int i = tid; i < NA_PAD; i += 1024) {
    bool act = false;
    u64 key = 0;
    if (i < NA) {
      key = sA[i];
      unsigned u = (unsigned)(key >> 32);
      if (u < ustar) act = true;
      else if (u == ustar) {
        int r = 0;
        for (int t2 = 0; t2 < g; ++t2) r += (tielist[t2] < i);
        act = (r < kp);
      }
    }
    u64 mm = __ballot(act);
    if (mm) {
      int leader = __ffsll(mm) - 1;
      int base = 0;
      if (lane == leader) base = atomicAdd(&sh_cnt, (int)__popcll(mm));
      base = __shfl(base, leader, 64);
      if (act) sB[base + (int)__popcll(mm & ((1ULL << lane) - 1))] = key;
    }
  }
  __syncthreads();

  // ---- phase 3: hybrid bitonic sort of 2048 u64 keys ----
  u64 e0 = sB[tid];
  u64 e1 = sB[tid + 1024];
  for (int kk = 2; kk <= CANDN; kk <<= 1) {
    for (int j = kk >> 1; j > 0; j >>= 1) {
      if (j == 1024) {
        u64 mn = (e0 < e1) ? e0 : e1;
        u64 mx = (e0 < e1) ? e1 : e0;
        e0 = mn; e1 = mx;
      } else if (j >= 64) {
        sB[tid] = e0;
        sB[tid + 1024] = e1;
        __syncthreads();
        u64 p0 = sB[tid ^ j];
        u64 p1 = sB[(tid + 1024) ^ j];
        e0 = cswap(e0, p0, tid, j, kk);
        e1 = cswap(e1, p1, tid + 1024, j, kk);
        __syncthreads();
      } else {
        u64 p0 = shflx64(e0, j);
        u64 p1 = shflx64(e1, j);
        e0 = cswap(e0, p0, tid, j, kk);
        e1 = cswap(e1, p1, tid + 1024, j, kk);
      }
    }
  }

  // ---- phase 4: prep (sA reused: skeys is dead) ----
  float4* nmsb = (float4*)sA;                       // 2048*16 = 32768
  float* areaA = (float*)((char*)sA + 32768);       // 2048*4  =  8192
  u64* skey2 = (u64*)((char*)sA + 40960);           // 2048*8  = 16384
  int* idxbuf = (int*)((char*)sA + 57344);          // 300*4   =  1200 (<=67200)
  const float* pb = pred + (size_t)b * (NCH * NA);
  float inv = (float)(1.0 / (double)imgsz[0]);

#pragma unroll
  for (int half = 0; half < 2; ++half) {
    u64 key = half ? e1 : e0;
    int s = tid + half * 1024;
    int idx = (int)(unsigned)(key & 0xFFFFFFFFu);
    float score = __uint_as_float(~(unsigned)(key >> 32));
    float x = pb[0 * NA + idx];
    float y = pb[1 * NA + idx];
    float w = pb[2 * NA + idx];
    float h = pb[3 * NA + idx];
    float hw = __fmul_rn(w, 0.5f);
    float hh = __fmul_rn(h, 0.5f);
    float x1 = __fsub_rn(x, hw);
    float y1 = __fsub_rn(y, hh);
    float x2 = __fadd_rn(x, hw);
    float y2 = __fadd_rn(y, hh);
    float clsf = (float)clsg[(size_t)b * NA + idx];
    float nx1 = __fadd_rn(__fmul_rn(x1, inv), clsf);
    float ny1 = __fadd_rn(__fmul_rn(y1, inv), clsf);
    float nx2 = __fadd_rn(__fmul_rn(x2, inv), clsf);
    float ny2 = __fadd_rn(__fmul_rn(y2, inv), clsf);
    float ar = __fmul_rn(__fsub_rn(nx2, nx1), __fsub_rn(ny2, ny1));
    nmsb[s] = make_float4(nx1, ny1, nx2, ny2);
    areaA[s] = ar;
    skey2[s] = key;
    u64 bal = __ballot(score > 0.25f);
    if (lane == 0) vmask[half * 16 + wv] = bal;
  }
  __syncthreads();

  // ---- phase 5: chunked NMS with lazy IoU ----
  u64* Mrows = sB;  // transposed [w][64]: Mrows[w*64 + r]
  const double THR = 0x1.CCCCCC8p-2;  // 0.45f + 2^-26 exactly
#pragma unroll 1
  for (int c = 0; c < 32; ++c) {
    __syncthreads();                 // bar A: K/cnt from prev chunk visible
    if (sh_nms >= MAXDET) break;     // uniform
    // 16 waves compute chunk-c M words: wave wv owns rows 4wv..4wv+3
#pragma unroll 1
    for (int rr = 0; rr < 4; ++rr) {
      int r = (wv << 2) + rr;
      int jg = (c << 6) + r;
      float4 bi = nmsb[jg];
      float ai = areaA[jg];
      for (int w = 0; w <= c; ++w) {
        int j = (w << 6) + lane;
        float4 bj = nmsb[j];
        float aj = areaA[j];
        float ix1 = fmaxf(bi.x, bj.x);
        float iy1 = fmaxf(bi.y, bj.y);
        float ix2 = fminf(bi.z, bj.z);
        float iy2 = fminf(bi.w, bj.w);
        float iw = fmaxf(__fsub_rn(ix2, ix1), 0.0f);
        float ih = fmaxf(__fsub_rn(iy2, iy1), 0.0f);
        float inter = __fmul_rn(iw, ih);
        float den = __fadd_rn(__fsub_rn(__fadd_rn(ai, aj), inter), 1e-7f);
        bool sup = (double)inter > THR * (double)den;
        u64 bb = __ballot(sup);
        if (lane == 0) Mrows[(w << 6) + r] = bb;
      }
    }
    __syncthreads();                 // bar B: Mrows ready
    if (wv == 0) {                   // wave 0 scans chunk c
      u64 vw = vmask[c];
      bool tent = ((vw >> lane) & 1ULL) != 0ULL;
      u64 acc = 0ULL;
      for (int w = 0; w < c; ++w) acc |= (K_lds[w] & Mrows[(w << 6) + lane]);
      tent = tent && (acc == 0ULL);
      u64 col = Mrows[(c << 6) + lane];
      u64 keptloc = 0ULL;
      int cnt = sh_nms;
      while (true) {
        bool alive = tent && ((keptloc & col) == 0ULL);
        u64 bb = __ballot(alive);
        if (bb == 0ULL) break;
        int f = __ffsll(bb) - 1;
        keptloc |= (1ULL << f);
        tent = tent && (lane != f);  // self-clear (diagonal may be 0)
        if (lane == 0) idxbuf[cnt] = (c << 6) + f;
        cnt++;
        if (cnt >= MAXDET) break;
      }
      if (lane == 0) { K_lds[c] = keptloc; sh_nms = cnt; }
    }
  }
  __syncthreads();

  // ---- phase 6: output (re-gather, identical rounding ops -> bit-exact) ----
  int total = sh_nms;
  if (tid < MAXDET) {
    float vals[6] = {0.f, 0.f, 0.f, 0.f, 0.f, 0.f};
    if (tid < total) {
      int gk = idxbuf[tid];
      u64 key = skey2[gk];
      int idx = (int)(unsigned)(key & 0xFFFFFFFFu);
      float score = __uint_as_float(~(unsigned)(key >> 32));
      float x = pb[0 * NA + idx];
      float y = pb[1 * NA + idx];
      float w = pb[2 * NA + idx];
      float h = pb[3 * NA + idx];
      float hw = __fmul_rn(w, 0.5f);
      float hh = __fmul_rn(h, 0.5f);
      vals[0] = __fsub_rn(x, hw);
      vals[1] = __fsub_rn(y, hh);
      vals[2] = __fadd_rn(x, hw);
      vals[3] = __fadd_rn(y, hh);
      vals[4] = score;
      vals[5] = (float)clsg[(size_t)b * NA + idx];
    }
#pragma unroll
    for (int q = 0; q < 6; ++q)
      out[((size_t)(b * MAXDET) + tid) * 6 + q] = vals[q];
  }
}

extern "C" void kernel_launch(void* const* d_in, const int* in_sizes, int n_in,
                              void* d_out, int out_size, void* d_ws, size_t ws_size,
                              hipStream_t stream) {
  (void)in_sizes; (void)n_in; (void)out_size; (void)ws_size;
  const float* pred = (const float*)d_in[0];
  const int* imgsz = (const int*)d_in[1];
  char* ws = (char*)d_ws;
  u64* keys = (u64*)(ws + OFF_KEYS);
  int* cls = (int*)(ws + OFF_CLS);
  float* out = (float*)d_out;

  score_kernel<<<dim3((NA + 255) / 256, NB), 256, 0, stream>>>(pred, keys, cls);
  fused_kernel<<<NB, 1024, 0, stream>>>(keys, cls, pred, imgsz, out);
}

// Round 8
// 108.626 us; speedup vs baseline: 2.3132x; 1.0231x over previous
//
#include <hip/hip_runtime.h>
#include <stdint.h>

#define NB 16
#define NA 8400
#define NA_PAD 9216
#define NCH 84
#define NCLS 80
#define CANDN 2048
#define MAXDET 300

typedef unsigned long long u64;

// ---------------- workspace layout (bytes) ----------------
static const size_t OFF_KEYS = 0;        // 16*8400*8 = 1075200
static const size_t OFF_CLS  = 1075200;  // 16*8400*4 = 537600

// ---------- kernel 1: per-anchor class max + argmax, build sort key ----------
__global__ __launch_bounds__(256) void score_kernel(const float* __restrict__ pred,
                                                    u64* __restrict__ keys,
                                                    int* __restrict__ cls) {
  int a = blockIdx.x * 256 + threadIdx.x;
  int b = blockIdx.y;
  if (a >= NA) return;
  const float* p = pred + (size_t)b * (NCH * NA) + 4 * NA + a;
  float best = p[0];
  int bc = 0;
#pragma unroll 8
  for (int c = 1; c < NCLS; ++c) {
    float v = p[(size_t)c * NA];
    if (v > best) { best = v; bc = c; }  // strict > : first-index argmax
  }
  // descending score, ascending index on ties, via ascending uint64 sort
  keys[b * NA + a] = (((u64)(~__float_as_uint(best))) << 32) | (unsigned int)a;
  cls[b * NA + a] = bc;
}

__device__ inline u64 shflx64(u64 v, int m) {
  int lo = __shfl_xor((int)(unsigned)(v & 0xFFFFFFFFu), m, 64);
  int hi = __shfl_xor((int)(unsigned)(v >> 32), m, 64);
  return (((u64)(unsigned)hi) << 32) | (unsigned)lo;
}

__device__ inline u64 cswap(u64 a, u64 b, int s, int j, int kk) {
  bool low = (s & j) == 0;
  bool asc = (s & kk) == 0;
  bool takeMin = (low == asc);
  u64 mn = (a < b) ? a : b;
  u64 mx = (a < b) ? b : a;
  return takeMin ? mn : mx;
}

// ---------- kernel 2: fused select + sort + prep + kept-list NMS + output ----------
__global__ __launch_bounds__(1024) void fused_kernel(const u64* __restrict__ keys,
                                                     const int* __restrict__ clsg,
                                                     const float* __restrict__ pred,
                                                     const int* __restrict__ imgsz,
                                                     float* __restrict__ out) {
  __shared__ alignas(16) u64 sA[NA];     // 67200 B: skeys; later nmsb/area/skey2/idxbuf
  __shared__ alignas(16) u64 sB[CANDN];  // 16384 B: sortbuf; later diag/supm
  __shared__ int hist[256];
  __shared__ int cum[256];
  __shared__ int tielist[1024];
  __shared__ u64 vmask[32];
  __shared__ unsigned sh_prefix;
  __shared__ int sh_k, sh_g, sh_cnt, sh_nms;

  int b = blockIdx.x;
  int tid = threadIdx.x;
  int lane = tid & 63;
  int wv = tid >> 6;

  if (tid == 0) { sh_prefix = 0; sh_k = CANDN; sh_g = 0; sh_cnt = 0; sh_nms = 0; }

  // ---- phase 1: 4-pass radix select on u = key>>32 (pass 0 fused with load) ----
  unsigned prefix = 0;
  int k = CANDN;
  for (int shift = 24; shift >= 0; shift -= 8) {
    if (tid < 256) hist[tid] = 0;
    __syncthreads();
    unsigned pmask = (shift == 24) ? 0u : (0xFFFFFFFFu << (shift + 8));
    for (int i = tid; i < NA_PAD; i += 1024) {
      bool act = false;
      int d = 0;
      if (i < NA) {
        u64 key;
        if (shift == 24) {
          key = keys[(size_t)b * NA + i];
          sA[i] = key;
          act = true;
        } else {
          key = sA[i];
          act = (((unsigned)(key >> 32)) & pmask) == prefix;
        }
        d = (int)((((unsigned)(key >> 32)) >> shift) & 255);
      }
      // wave-aggregate same-digit counts (scores cluster -> few hot bins)
      u64 m = __ballot(act);
      if (m) {
#pragma unroll
        for (int bit = 0; bit < 8; ++bit) {
          u64 bb = __ballot((d >> bit) & 1);
          m &= ((d >> bit) & 1) ? bb : ~bb;
        }
        if (act && (m & ((1ULL << lane) - 1)) == 0ULL)
          atomicAdd(&hist[d], (int)__popcll(m));
      }
    }
    __syncthreads();
    if (tid < 64) {  // inclusive scan of 256 bins by wave 0
      int v0 = hist[tid * 4 + 0], v1 = hist[tid * 4 + 1];
      int v2 = hist[tid * 4 + 2], v3 = hist[tid * 4 + 3];
      int s0 = v0, s1 = s0 + v1, s2 = s1 + v2, s3 = s2 + v3;
      int tot = s3;
      for (int off = 1; off < 64; off <<= 1) {
        int t = __shfl_up(tot, off, 64);
        if (tid >= off) tot += t;
      }
      int base = tot - s3;
      cum[tid * 4 + 0] = base + s0;
      cum[tid * 4 + 1] = base + s1;
      cum[tid * 4 + 2] = base + s2;
      cum[tid * 4 + 3] = base + s3;
    }
    __syncthreads();
    if (tid < 256) {
      int c = cum[tid];
      int cprev = (tid == 0) ? 0 : cum[tid - 1];
      if (c >= k && cprev < k) {
        sh_prefix = prefix | ((unsigned)tid << shift);
        sh_k = k - cprev;
      }
    }
    __syncthreads();
    prefix = sh_prefix;
    k = sh_k;
  }
  unsigned ustar = prefix;
  int kp = k;

  // ---- phase 2: boundary tie-fix + compaction ----
  for (int i = tid; i < NA; i += 1024) {
    unsigned u = (unsigned)(sA[i] >> 32);
    if (u == ustar) {
      int p = atomicAdd(&sh_g, 1);
      if (p < 1024) tielist[p] = i;
    }
  }
  __syncthreads();
  int g = sh_g < 1024 ? sh_g : 1024;

  for (int i = tid; i < NA_PAD; i += 1024) {
    bool act = false;
    u64 key = 0;
    if (i < NA) {
      key = sA[i];
      unsigned u = (unsigned)(key >> 32);
      if (u < ustar) act = true;
      else if (u == ustar) {
        int r = 0;
        for (int t2 = 0; t2 < g; ++t2) r += (tielist[t2] < i);
        act = (r < kp);
      }
    }
    u64 mm = __ballot(act);
    if (mm) {
      int leader = __ffsll(mm) - 1;
      int base = 0;
      if (lane == leader) base = atomicAdd(&sh_cnt, (int)__popcll(mm));
      base = __shfl(base, leader, 64);
      if (act) sB[base + (int)__popcll(mm & ((1ULL << lane) - 1))] = key;
    }
  }
  __syncthreads();

  // ---- phase 3: hybrid bitonic sort of 2048 u64 keys ----
  u64 e0 = sB[tid];
  u64 e1 = sB[tid + 1024];
  for (int kk = 2; kk <= CANDN; kk <<= 1) {
    for (int j = kk >> 1; j > 0; j >>= 1) {
      if (j == 1024) {
        u64 mn = (e0 < e1) ? e0 : e1;
        u64 mx = (e0 < e1) ? e1 : e0;
        e0 = mn; e1 = mx;
      } else if (j >= 64) {
        sB[tid] = e0;
        sB[tid + 1024] = e1;
        __syncthreads();
        u64 p0 = sB[tid ^ j];
        u64 p1 = sB[(tid + 1024) ^ j];
        e0 = cswap(e0, p0, tid, j, kk);
        e1 = cswap(e1, p1, tid + 1024, j, kk);
        __syncthreads();
      } else {
        u64 p0 = shflx64(e0, j);
        u64 p1 = shflx64(e1, j);
        e0 = cswap(e0, p0, tid, j, kk);
        e1 = cswap(e1, p1, tid + 1024, j, kk);
      }
    }
  }

  // ---- phase 4: prep (sA reused: skeys is dead) ----
  float4* nmsb = (float4*)sA;                       // 2048*16 = 32768
  float* areaA = (float*)((char*)sA + 32768);       // 2048*4  =  8192
  u64* skey2 = (u64*)((char*)sA + 40960);           // 2048*8  = 16384
  int* idxbuf = (int*)((char*)sA + 57344);          // 300*4   =  1200 (<=67200)
  const float* pb = pred + (size_t)b * (NCH * NA);
  float inv = (float)(1.0 / (double)imgsz[0]);

#pragma unroll
  for (int half = 0; half < 2; ++half) {
    u64 key = half ? e1 : e0;
    int s = tid + half * 1024;
    int idx = (int)(unsigned)(key & 0xFFFFFFFFu);
    float score = __uint_as_float(~(unsigned)(key >> 32));
    float x = pb[0 * NA + idx];
    float y = pb[1 * NA + idx];
    float w = pb[2 * NA + idx];
    float h = pb[3 * NA + idx];
    float hw = __fmul_rn(w, 0.5f);
    float hh = __fmul_rn(h, 0.5f);
    float x1 = __fsub_rn(x, hw);
    float y1 = __fsub_rn(y, hh);
    float x2 = __fadd_rn(x, hw);
    float y2 = __fadd_rn(y, hh);
    float clsf = (float)clsg[(size_t)b * NA + idx];
    float nx1 = __fadd_rn(__fmul_rn(x1, inv), clsf);
    float ny1 = __fadd_rn(__fmul_rn(y1, inv), clsf);
    float nx2 = __fadd_rn(__fmul_rn(x2, inv), clsf);
    float ny2 = __fadd_rn(__fmul_rn(y2, inv), clsf);
    float ar = __fmul_rn(__fsub_rn(nx2, nx1), __fsub_rn(ny2, ny1));
    nmsb[s] = make_float4(nx1, ny1, nx2, ny2);
    areaA[s] = ar;
    skey2[s] = key;
    u64 bal = __ballot(score > 0.25f);
    if (lane == 0) vmask[half * 16 + wv] = bal;
  }
  __syncthreads();

  // ---- phase 5: chunked NMS, IoU only vs kept list + in-chunk diagonal ----
  // Cross-chunk suppression of row r needs IoU vs KEPT candidates only
  // (<=300, in idxbuf) -- not vs all earlier candidates. In-chunk 64x64
  // diagonal word computed as before. IoU symmetric & bit-exact (max/min/
  // fadd commutative), so decisions match the reference exactly.
  u64* diag = sB;        // [64] who-suppresses-whom within chunk
  u64* supm = sB + 64;   // [16] per-wave cross-chunk suppression ballots
  const double THR = 0x1.CCCCCC8p-2;  // 0.45f + 2^-26 exactly
#pragma unroll 1
  for (int c = 0; c < 32; ++c) {
    __syncthreads();                 // keeps/sh_nms from prev chunk visible
    int nk0 = sh_nms;
    if (nk0 >= MAXDET) break;        // uniform
    int rg = (c << 6) + lane;
    float4 br = nmsb[rg];            // this thread's row box (lane = row)
    float arr = areaA[rg];
    // cross-chunk: row vs kept list, strided over 16 waves (broadcast reads)
    bool sup = false;
    for (int q = wv; q < nk0; q += 16) {
      int kq = idxbuf[q];
      float4 bk = nmsb[kq];
      float ak = areaA[kq];
      float ix1 = fmaxf(br.x, bk.x);
      float iy1 = fmaxf(br.y, bk.y);
      float ix2 = fminf(br.z, bk.z);
      float iy2 = fminf(br.w, bk.w);
      float iw = fmaxf(__fsub_rn(ix2, ix1), 0.0f);
      float ih = fmaxf(__fsub_rn(iy2, iy1), 0.0f);
      float inter = __fmul_rn(iw, ih);
      float den = __fadd_rn(__fsub_rn(__fadd_rn(arr, ak), inter), 1e-7f);
      sup = sup || ((double)inter > THR * (double)den);
    }
    u64 sm = __ballot(sup);
    if (lane == 0) supm[wv] = sm;
    // in-chunk diagonal: wave wv computes rows 4wv..4wv+3 vs all 64 lanes
#pragma unroll
    for (int rr = 0; rr < 4; ++rr) {
      int r = (wv << 2) + rr;
      float4 bi = nmsb[(c << 6) + r];
      float ai = areaA[(c << 6) + r];
      float ix1 = fmaxf(bi.x, br.x);
      float iy1 = fmaxf(bi.y, br.y);
      float ix2 = fminf(bi.z, br.z);
      float iy2 = fminf(bi.w, br.w);
      float iw = fmaxf(__fsub_rn(ix2, ix1), 0.0f);
      float ih = fmaxf(__fsub_rn(iy2, iy1), 0.0f);
      float inter = __fmul_rn(iw, ih);
      float den = __fadd_rn(__fsub_rn(__fadd_rn(ai, arr), inter), 1e-7f);
      bool supd = (double)inter > THR * (double)den;
      u64 bb = __ballot(supd);
      if (lane == 0) diag[r] = bb;
    }
    __syncthreads();                 // supm/diag ready
    if (wv == 0) {                   // wave 0 resolves chunk c greedily
      u64 orsup = 0ULL;
#pragma unroll
      for (int w = 0; w < 16; ++w) orsup |= supm[w];
      bool tent = (((vmask[c] >> lane) & 1ULL) != 0ULL) &&
                  (((orsup >> lane) & 1ULL) == 0ULL);
      u64 col = diag[lane];          // bit k: in-chunk k suppresses me
      u64 keptloc = 0ULL;
      int cnt = nk0;
      while (true) {
        bool alive = tent && ((keptloc & col) == 0ULL);
        u64 bb = __ballot(alive);
        if (bb == 0ULL) break;
        int f = __ffsll(bb) - 1;     // lowest alive = next greedy keep
        keptloc |= (1ULL << f);
        tent = tent && (lane != f);  // self-clear (diagonal may be 0)
        if (lane == 0) idxbuf[cnt] = (c << 6) + f;
        cnt++;
        if (cnt >= MAXDET) break;
      }
      if (lane == 0) sh_nms = cnt;
    }
  }
  __syncthreads();

  // ---- phase 6: output (re-gather, identical rounding ops -> bit-exact) ----
  int total = sh_nms;
  if (tid < MAXDET) {
    float vals[6] = {0.f, 0.f, 0.f, 0.f, 0.f, 0.f};
    if (tid < total) {
      int gk = idxbuf[tid];
      u64 key = skey2[gk];
      int idx = (int)(unsigned)(key & 0xFFFFFFFFu);
      float score = __uint_as_float(~(unsigned)(key >> 32));
      float x = pb[0 * NA + idx];
      float y = pb[1 * NA + idx];
      float w = pb[2 * NA + idx];
      float h = pb[3 * NA + idx];
      float hw = __fmul_rn(w, 0.5f);
      float hh = __fmul_rn(h, 0.5f);
      vals[0] = __fsub_rn(x, hw);
      vals[1] = __fsub_rn(y, hh);
      vals[2] = __fadd_rn(x, hw);
      vals[3] = __fadd_rn(y, hh);
      vals[4] = score;
      vals[5] = (float)clsg[(size_t)b * NA + idx];
    }
#pragma unroll
    for (int q = 0; q < 6; ++q)
      out[((size_t)(b * MAXDET) + tid) * 6 + q] = vals[q];
  }
}

extern "C" void kernel_launch(void* const* d_in, const int* in_sizes, int n_in,
                              void* d_out, int out_size, void* d_ws, size_t ws_size,
                              hipStream_t stream) {
  (void)in_sizes; (void)n_in; (void)out_size; (void)ws_size;
  const float* pred = (const float*)d_in[0];
  const int* imgsz = (const int*)d_in[1];
  char* ws = (char*)d_ws;
  u64* keys = (u64*)(ws + OFF_KEYS);
  int* cls = (int*)(ws + OFF_CLS);
  float* out = (float*)d_out;

  score_kernel<<<dim3((NA + 255) / 256, NB), 256, 0, stream>>>(pred, keys, cls);
  fused_kernel<<<NB, 1024, 0, stream>>>(keys, cls, pred, imgsz, out);
}